// Round 8
// baseline (351.370 us; speedup 1.0000x reference)
//
#include <hip/hip_runtime.h>
#include <hip/hip_bf16.h>

// Problem-fixed shapes (XLMRForTokenClassification: B=128, S=512, H=1024, L=9)
#define B_ 128
#define S_ 512
#define H_ 1024
#define L_ 9

#define NBLK 256        // 2 blocks per batch
#define NTHR 512        // 8 waves per block
#define WPB  8
#define SLOTS 3         // per-wave LDS row ring depth
#define REPS_IN 24      // DIAGNOSTIC: in-kernel idempotent reps -> top-5 slot

// DPP-based wave64 sum: total lands in lane 63.
#define DPP_ADD_(v, ctrl, rm, bm)                                              \
    v += __int_as_float(__builtin_amdgcn_update_dpp(                           \
        0, __float_as_int(v), ctrl, rm, bm, true))

__device__ __forceinline__ float wave_sum63(float v) {
    DPP_ADD_(v, 0x111, 0xf, 0xf);  // row_shr:1
    DPP_ADD_(v, 0x112, 0xf, 0xf);  // row_shr:2
    DPP_ADD_(v, 0x114, 0xf, 0xe);  // row_shr:4
    DPP_ADD_(v, 0x118, 0xf, 0xc);  // row_shr:8
    DPP_ADD_(v, 0x142, 0xa, 0xf);  // row_bcast:15 -> rows 1,3
    DPP_ADD_(v, 0x143, 0xc, 0xf);  // row_bcast:31 -> rows 2,3
    return v;
}

// ---------------------------------------------------------------------------
// Fused compute kernel (R7 structure), with an in-kernel rep loop for
// measurement. Each rep recomputes the identical result from unchanged
// inputs (registers bpev/lab/lmv/wreg/bl are loaded once; LDS arrays are
// rebuilt identically each rep; lsum is reset per rep) -> deterministic.
// ---------------------------------------------------------------------------
__global__ __launch_bounds__(NTHR, 2) void fused_kernel(
    const float* __restrict__ x,       // [B,S,H]
    const int*   __restrict__ labels,  // [B,S]
    const int*   __restrict__ lmask,   // [B,S]
    const int*   __restrict__ bpe,     // [B,S]
    const float* __restrict__ W,       // [L,H]
    const float* __restrict__ bias,    // [L]
    float* __restrict__ part_sum,      // [NBLK]
    float* __restrict__ part_cnt)      // [NBLK]
{
    const int tid  = threadIdx.x;
    const int lane = tid & 63;
    const int wv   = tid >> 6;
    const int b    = blockIdx.x >> 1;
    const int half = blockIdx.x & 1;

    __shared__ float    ring[WPB][SLOTS][H_];   // 96 KB, per-wave private
    __shared__ int      wcnt[WPB], wcnt2[WPB];
    __shared__ int      srcbuf[S_];
    __shared__ unsigned items[S_];
    __shared__ float    red[WPB], redc[WPB];

    // ---- one-time global loads (registers survive across reps) ----
    const int gpos = b * S_ + tid;
    const int bpev = bpe[gpos];
    const int lab  = labels[gpos];
    const int lmv  = lmask[gpos];

    const float4* W4 = reinterpret_cast<const float4*>(W);
    float4 wreg[L_][4];
#pragma unroll
    for (int l = 0; l < L_; ++l)
#pragma unroll
        for (int k = 0; k < 4; ++k)
            wreg[l][k] = W4[l * (H_ / 4) + lane + 64 * k];
    float bl[L_];
#pragma unroll
    for (int l = 0; l < L_; ++l) bl[l] = bias[l];

    const unsigned long long lmlt = (1ull << lane) - 1ull;
    const float* xb = x + (size_t)b * S_ * H_;

    float lsum = 0.f, bnll = 0.f, bc = 0.f;

    for (int rep = 0; rep < REPS_IN; ++rep) {
        // ---- phase A: per-batch scans (identical every rep) ----
        const int vv = (bpev == 1) ? 1 : 0;
        const unsigned long long ball = __ballot(vv != 0);
        const int rank = (int)__popcll(ball & lmlt);
        if (lane == 0) wcnt[wv] = (int)__popcll(ball);
        __syncthreads();
        int prefix = 0, n_valid = 0;
#pragma unroll
        for (int w = 0; w < WPB; ++w) {
            const int c = wcnt[w];
            if (w < wv) prefix += c;
            n_valid += c;
        }
        if (vv) srcbuf[prefix + rank] = tid;
        __syncthreads();

        const bool act = (lmv == 1) && (lab != 0);
        const bool rowitem = act && (tid < n_valid);
        const unsigned long long ball2 = __ballot(rowitem);
        const int rank2 = (int)__popcll(ball2 & lmlt);
        if (lane == 0) wcnt2[wv] = (int)__popcll(ball2);
        __syncthreads();
        int prefix2 = 0, m = 0;
#pragma unroll
        for (int w = 0; w < WPB; ++w) {
            const int c = wcnt2[w];
            if (w < wv) prefix2 += c;
            m += c;
        }
        if (rowitem)
            items[prefix2 + rank2] =
                ((unsigned)srcbuf[tid] << 4) | (unsigned)lab;

        bnll = 0.f; bc = 0.f;
        if (half == 0) {
            if (act && tid >= n_valid) {
                float mx = bl[0];
#pragma unroll
                for (int l = 1; l < L_; ++l) mx = fmaxf(mx, bl[l]);
                float se = 0.f;
#pragma unroll
                for (int l = 0; l < L_; ++l) se += __expf(bl[l] - mx);
                bnll = mx + __logf(se) - bl[lab];
            }
            bc = act ? 1.f : 0.f;
        }
        __syncthreads();   // items[] visible

        // ---- phase B ----
        const int p  = half + 2 * wv;
        const int nt = (m > p) ? ((m - p + 15) >> 4) : 0;

        const int midx = p + 16 * lane;
        unsigned ereg = (midx < m) ? items[midx] : 0u;

        lsum = 0.f;   // reset each rep -> idempotent

        auto issue_row = [&](int slot, int t) {
            const unsigned e =
                (unsigned)__builtin_amdgcn_readlane((int)ereg, t);
            const float* g = xb + (size_t)(e >> 4) * H_ + (lane << 2);
            float* l = &ring[wv][slot][0];
#pragma unroll
            for (int k = 0; k < 4; ++k) {
                __builtin_amdgcn_global_load_lds(
                    (const __attribute__((address_space(1))) void*)(g + k * 256),
                    (__attribute__((address_space(3))) void*)(l + k * 256),
                    16, 0, 0);
            }
        };

        auto compute_from = [&](int slot, int t) {
            const float4* sp =
                reinterpret_cast<const float4*>(&ring[wv][slot][0]);
            const float4 v0 = sp[lane];
            const float4 v1 = sp[lane + 64];
            const float4 v2 = sp[lane + 128];
            const float4 v3 = sp[lane + 192];
            float acc[L_];
#pragma unroll
            for (int l = 0; l < L_; ++l) {
                acc[l] = v0.x * wreg[l][0].x + v0.y * wreg[l][0].y
                       + v0.z * wreg[l][0].z + v0.w * wreg[l][0].w
                       + v1.x * wreg[l][1].x + v1.y * wreg[l][1].y
                       + v1.z * wreg[l][1].z + v1.w * wreg[l][1].w
                       + v2.x * wreg[l][2].x + v2.y * wreg[l][2].y
                       + v2.z * wreg[l][2].z + v2.w * wreg[l][2].w
                       + v3.x * wreg[l][3].x + v3.y * wreg[l][3].y
                       + v3.z * wreg[l][3].z + v3.w * wreg[l][3].w;
            }
#pragma unroll
            for (int l = 0; l < L_; ++l) acc[l] = wave_sum63(acc[l]);
            if (lane == 63) {
                const int lb =
                    (int)(__builtin_amdgcn_readlane((int)ereg, t) & 0xF);
                float lg[L_];
#pragma unroll
                for (int l = 0; l < L_; ++l) lg[l] = acc[l] + bl[l];
                float mx = lg[0];
#pragma unroll
                for (int l = 1; l < L_; ++l) mx = fmaxf(mx, lg[l]);
                float se = 0.f;
#pragma unroll
                for (int l = 0; l < L_; ++l) se += __expf(lg[l] - mx);
                float sel = lg[0];
#pragma unroll
                for (int l = 1; l < L_; ++l) sel = (lb == l) ? lg[l] : sel;
                lsum += mx + __logf(se) - sel;
            }
        };

        asm volatile("s_waitcnt vmcnt(0)" ::: "memory");

        if (nt > 0) {
            issue_row(0, 0);
            if (nt > 1) issue_row(1, 1);
            for (int t = 0; t < nt; ++t) {
                if (t + 2 < nt) issue_row((t + 2) % SLOTS, t + 2);
                if (t + 2 < nt) {
                    asm volatile("s_waitcnt vmcnt(8)" ::: "memory");
                } else if (t + 1 < nt) {
                    asm volatile("s_waitcnt vmcnt(4)" ::: "memory");
                } else {
                    asm volatile("s_waitcnt vmcnt(0)" ::: "memory");
                }
                __builtin_amdgcn_sched_barrier(0);
                compute_from(t % SLOTS, t);
            }
        }
    }

    // ---- block reduce -> partial stores (last rep's values) ----
    const float bs = wave_sum63(bnll);
    const float cs = wave_sum63(bc);
    if (lane == 63) { red[wv] = lsum + bs; redc[wv] = cs; }
    __syncthreads();
    if (tid == 0) {
        float a = 0.f, c = 0.f;
#pragma unroll
        for (int w = 0; w < WPB; ++w) { a += red[w]; c += redc[w]; }
        part_sum[blockIdx.x] = a;
        part_cnt[blockIdx.x] = c;
    }
}

// ---------------------------------------------------------------------------
// Finalize: reduce partials -> scalar loss
// ---------------------------------------------------------------------------
__global__ void finalize_kernel(const float* __restrict__ part_sum,
                                const float* __restrict__ part_cnt,
                                float* __restrict__ out) {
    const int lane = threadIdx.x;  // 64 threads
    float s = 0.f, c = 0.f;
    for (int i = lane; i < NBLK; i += 64) {
        s += part_sum[i];
        c += part_cnt[i];
    }
#pragma unroll
    for (int off = 32; off > 0; off >>= 1) {
        s += __shfl_xor(s, off, 64);
        c += __shfl_xor(c, off, 64);
    }
    if (lane == 0) out[0] = s / fmaxf(c, 1.0f);
}

extern "C" void kernel_launch(void* const* d_in, const int* in_sizes, int n_in,
                              void* d_out, int out_size, void* d_ws, size_t ws_size,
                              hipStream_t stream) {
    const float* x      = (const float*)d_in[0];  // [B,S,H] f32
    const int*   labels = (const int*)d_in[1];    // [B,S]
    const int*   lmask  = (const int*)d_in[2];    // [B,S]
    const int*   bpe    = (const int*)d_in[3];    // [B,S]
    const float* W      = (const float*)d_in[4];  // [L,H] f32
    const float* bias   = (const float*)d_in[5];  // [L]  f32

    // Workspace: part_sum[NBLK] | part_cnt[NBLK]
    float* part_sum = (float*)d_ws;
    float* part_cnt = part_sum + NBLK;

    fused_kernel<<<NBLK, NTHR, 0, stream>>>(
        x, labels, lmask, bpe, W, bias, part_sum, part_cnt);
    finalize_kernel<<<1, 64, 0, stream>>>(part_sum, part_cnt, (float*)d_out);
}

// Round 10
// 23.301 us; speedup vs baseline: 15.0798x; 15.0798x over previous
//
#include <hip/hip_runtime.h>
#include <hip/hip_bf16.h>

// Problem-fixed shapes (XLMRForTokenClassification: B=128, S=512, H=1024, L=9)
#define B_ 128
#define S_ 512
#define H_ 1024
#define L_ 9

#define NBLK 256        // 2 blocks per batch
#define NTHR 512        // 8 waves per block
#define WPB  8

#define WSTRIDE   1032  // padded W row stride in bf16 elems (2064 B)
#define WSTRIDE_B 2064

typedef __attribute__((ext_vector_type(8))) short short8;
typedef __attribute__((ext_vector_type(4))) float f32x4;

// DPP-based wave64 sum: total lands in lane 63.
#define DPP_ADD_(v, ctrl, rm, bm)                                              \
    v += __int_as_float(__builtin_amdgcn_update_dpp(                           \
        0, __float_as_int(v), ctrl, rm, bm, true))

__device__ __forceinline__ float wave_sum63(float v) {
    DPP_ADD_(v, 0x111, 0xf, 0xf);  // row_shr:1
    DPP_ADD_(v, 0x112, 0xf, 0xf);  // row_shr:2
    DPP_ADD_(v, 0x114, 0xf, 0xe);  // row_shr:4
    DPP_ADD_(v, 0x118, 0xf, 0xc);  // row_shr:8
    DPP_ADD_(v, 0x142, 0xa, 0xf);  // row_bcast:15 -> rows 1,3
    DPP_ADD_(v, 0x143, 0xc, 0xf);  // row_bcast:31 -> rows 2,3
    return v;
}

__device__ __forceinline__ unsigned pk_bf16(float lo, float hi) {
    union { __hip_bfloat162 h; unsigned u; } cv;
    cv.h = __float22bfloat162_rn(make_float2(lo, hi));
    return cv.u;
}

// ---------------------------------------------------------------------------
// Fused kernel. blockIdx -> (batch = blk>>1, half = blk&1).
// Phase A: ballot scans -> per-batch item list (meta=(src<<4)|lab) in LDS;
//   W staged once to LDS as bf16 [16][1032] (rows 9..15 zero); bias-only NLL
//   + active count (half==0 block only).
// Phase B: 16-item groups per wave via MFMA 16x16x32 bf16 (contiguous-8 k
//   per lane, the m92/m97-refchecked fragment pattern):
//   A-frag: lane l = row/item (l&15), k = (l>>4)*8+j  -- x loaded f32
//   direct-to-VGPR (8-deep rotating, fully unrolled), cvt_pk to bf16.
//   B-frag: lane l = col/class (l&15), k = (l>>4)*8+j -- ds_read_b128 from W.
//   D: row=(l>>4)*4+reg = item, col=l&15 = class (m89-verified layout).
//   Softmax: 4-step shfl_xor over the 16 class-lanes; NLL via class mask.
//   lsum is wave-reduced (DPP) before the lane-63 store  <-- R9 bug fix.
// ---------------------------------------------------------------------------
__global__ __launch_bounds__(NTHR, 2) void fused_kernel(
    const float* __restrict__ x,       // [B,S,H]
    const int*   __restrict__ labels,  // [B,S]
    const int*   __restrict__ lmask,   // [B,S]
    const int*   __restrict__ bpe,     // [B,S]
    const float* __restrict__ W,       // [L,H]
    const float* __restrict__ bias,    // [L]
    float* __restrict__ part_sum,      // [NBLK]
    float* __restrict__ part_cnt)      // [NBLK]
{
    const int tid  = threadIdx.x;
    const int lane = tid & 63;
    const int wv   = tid >> 6;
    const int b    = blockIdx.x >> 1;
    const int half = blockIdx.x & 1;
    const int cls  = lane & 15;
    const int qrt  = lane >> 4;

    __shared__ unsigned short Wl[16 * WSTRIDE];  // bf16 bits, 33 KB
    __shared__ int      wcnt[WPB], wcnt2[WPB];
    __shared__ int      srcbuf[S_];
    __shared__ unsigned items[S_];
    __shared__ float    red[WPB], redc[WPB];

    // ---- scan-critical int loads first ----
    const int gpos = b * S_ + tid;
    const int bpev = bpe[gpos];
    const int lab  = labels[gpos];
    const int lmv  = lmask[gpos];

    // ---- stage W -> LDS bf16 (pad rows 9..15 with zeros) ----
    for (int i = tid; i < L_ * H_; i += NTHR) {
        const int r = i >> 10, c = i & 1023;
        union { __hip_bfloat16 h; unsigned short u; } cv;
        cv.h = __float2bfloat16(W[i]);
        Wl[r * WSTRIDE + c] = cv.u;
    }
    for (int i = tid; i < (16 - L_) * H_; i += NTHR) {
        const int r = L_ + (i >> 10), c = i & 1023;
        Wl[r * WSTRIDE + c] = 0;
    }

    const float blane = (cls < L_) ? bias[cls] : 0.f;  // per-lane class bias
    float blv[L_];
#pragma unroll
    for (int l = 0; l < L_; ++l) blv[l] = bias[l];     // uniform (phase A)

    // ---- phase A: per-batch scans ----
    const unsigned long long lmlt = (1ull << lane) - 1ull;

    const int vv = (bpev == 1) ? 1 : 0;
    const unsigned long long ball = __ballot(vv != 0);
    const int rank = (int)__popcll(ball & lmlt);
    if (lane == 0) wcnt[wv] = (int)__popcll(ball);
    __syncthreads();
    int prefix = 0, n_valid = 0;
#pragma unroll
    for (int w = 0; w < WPB; ++w) {
        const int c = wcnt[w];
        if (w < wv) prefix += c;
        n_valid += c;
    }
    if (vv) srcbuf[prefix + rank] = tid;
    __syncthreads();

    const bool act = (lmv == 1) && (lab != 0);
    const bool rowitem = act && (tid < n_valid);
    const unsigned long long ball2 = __ballot(rowitem);
    const int rank2 = (int)__popcll(ball2 & lmlt);
    if (lane == 0) wcnt2[wv] = (int)__popcll(ball2);
    __syncthreads();
    int prefix2 = 0, m = 0;
#pragma unroll
    for (int w = 0; w < WPB; ++w) {
        const int c = wcnt2[w];
        if (w < wv) prefix2 += c;
        m += c;
    }
    if (rowitem)
        items[prefix2 + rank2] = ((unsigned)srcbuf[tid] << 4) | (unsigned)lab;

    // bias-only NLL (zeroed rows: logits == bias) + denominator (half==0 only)
    float bnll = 0.f, bc = 0.f;
    if (half == 0) {
        if (act && tid >= n_valid) {
            float mx = blv[0];
#pragma unroll
            for (int l = 1; l < L_; ++l) mx = fmaxf(mx, blv[l]);
            float se = 0.f;
#pragma unroll
            for (int l = 0; l < L_; ++l) se += __expf(blv[l] - mx);
            bnll = mx + __logf(se) - blv[lab];
        }
        bc = act ? 1.f : 0.f;
    }
    __syncthreads();   // items[] and Wl[] visible

    // ---- phase B: 16-item groups via MFMA ----
    const float* xb = x + (size_t)b * (S_ * H_);
    const int ngroups = (m + 15) >> 4;
    float lsum = 0.f;

    for (int g = 2 * wv + half; g < ngroups; g += 16) {
        // A-side: my lane's row = item (g*16 + cls)
        const int j16 = (g << 4) + cls;
        const unsigned meta = (j16 < m) ? items[j16] : 0u;
        const float* rp = xb + ((size_t)(meta >> 4) << 10) + (qrt << 3);

        // epilogue metadata: item (g*16 + qrt*4 + r) per accumulator reg
        int labr[4], vldr[4];
#pragma unroll
        for (int r = 0; r < 4; ++r) {
            const int jr = (g << 4) + (qrt << 2) + r;
            const unsigned mr = (jr < m) ? items[jr] : 0u;
            labr[r] = (int)(mr & 0xFu);
            vldr[r] = (jr < m) ? 1 : 0;
        }

        // 8-deep rotating f32 prefetch (fully unrolled -> static indices)
        float4 fb[8][2];
#pragma unroll
        for (int i = 0; i < 8; ++i) {
            fb[i][0] = *reinterpret_cast<const float4*>(rp + i * 32);
            fb[i][1] = *reinterpret_cast<const float4*>(rp + i * 32 + 4);
        }

        f32x4 acc = {0.f, 0.f, 0.f, 0.f};
        const char* wbase = reinterpret_cast<const char*>(Wl)
                          + cls * WSTRIDE_B + qrt * 16;
#pragma unroll
        for (int t = 0; t < 32; ++t) {
            const short8 bfrag =
                *reinterpret_cast<const short8*>(wbase + t * 64);
            const float4 u = fb[t & 7][0];
            const float4 v = fb[t & 7][1];
            union { unsigned u32[4]; short8 s; } af;
            af.u32[0] = pk_bf16(u.x, u.y);
            af.u32[1] = pk_bf16(u.z, u.w);
            af.u32[2] = pk_bf16(v.x, v.y);
            af.u32[3] = pk_bf16(v.z, v.w);
            acc = __builtin_amdgcn_mfma_f32_16x16x32_bf16(
                af.s, bfrag, acc, 0, 0, 0);
            if (t + 8 < 32) {
                fb[t & 7][0] =
                    *reinterpret_cast<const float4*>(rp + (t + 8) * 32);
                fb[t & 7][1] =
                    *reinterpret_cast<const float4*>(rp + (t + 8) * 32 + 4);
            }
        }

        // epilogue: per-reg softmax over the 16 class-lanes
#pragma unroll
        for (int r = 0; r < 4; ++r) {
            float lg = acc[r] + blane;
            if (cls >= L_) lg = -1e30f;
            float mx = lg;
#pragma unroll
            for (int msk = 1; msk < 16; msk <<= 1)
                mx = fmaxf(mx, __shfl_xor(mx, msk, 64));
            const float e = __expf(lg - mx);
            float se = e;
#pragma unroll
            for (int msk = 1; msk < 16; msk <<= 1)
                se += __shfl_xor(se, msk, 64);
            const float lse = mx + __logf(se);
            if (vldr[r] && cls == labr[r]) lsum += lse - lg;
        }
    }

    // ---- block reduce -> partial stores (lsum is spread across lanes:
    //      wave-reduce it BEFORE the lane-63 store — this was the R9 bug) ----
    const float ls = wave_sum63(lsum);
    const float bs = wave_sum63(bnll);
    const float cs = wave_sum63(bc);
    if (lane == 63) { red[wv] = ls + bs; redc[wv] = cs; }
    __syncthreads();
    if (tid == 0) {
        float a = 0.f, c = 0.f;
#pragma unroll
        for (int w = 0; w < WPB; ++w) { a += red[w]; c += redc[w]; }
        part_sum[blockIdx.x] = a;
        part_cnt[blockIdx.x] = c;
    }
}

// ---------------------------------------------------------------------------
// Finalize: reduce partials -> scalar loss
// ---------------------------------------------------------------------------
__global__ void finalize_kernel(const float* __restrict__ part_sum,
                                const float* __restrict__ part_cnt,
                                float* __restrict__ out) {
    const int lane = threadIdx.x;  // 64 threads
    float s = 0.f, c = 0.f;
    for (int i = lane; i < NBLK; i += 64) {
        s += part_sum[i];
        c += part_cnt[i];
    }
#pragma unroll
    for (int off = 32; off > 0; off >>= 1) {
        s += __shfl_xor(s, off, 64);
        c += __shfl_xor(c, off, 64);
    }
    if (lane == 0) out[0] = s / fmaxf(c, 1.0f);
}

extern "C" void kernel_launch(void* const* d_in, const int* in_sizes, int n_in,
                              void* d_out, int out_size, void* d_ws, size_t ws_size,
                              hipStream_t stream) {
    const float* x      = (const float*)d_in[0];  // [B,S,H] f32
    const int*   labels = (const int*)d_in[1];    // [B,S]
    const int*   lmask  = (const int*)d_in[2];    // [B,S]
    const int*   bpe    = (const int*)d_in[3];    // [B,S]
    const float* W      = (const float*)d_in[4];  // [L,H] f32
    const float* bias   = (const float*)d_in[5];  // [L]  f32

    // Workspace: part_sum[NBLK] | part_cnt[NBLK]
    float* part_sum = (float*)d_ws;
    float* part_cnt = part_sum + NBLK;

    fused_kernel<<<NBLK, NTHR, 0, stream>>>(
        x, labels, lmask, bpe, W, bias, part_sum, part_cnt);
    finalize_kernel<<<1, 64, 0, stream>>>(part_sum, part_cnt, (float*)d_out);
}